// Round 1
// 66.426 us; speedup vs baseline: 1.0141x; 1.0141x over previous
//
#include <hip/hip_runtime.h>
#include <math.h>

#define BLOCK 256
#define SPLIT 4            // threads cooperating per pixel-group
#define PPT   4            // pixels per thread

__device__ __forceinline__ float rcp1(float x)  { return __builtin_amdgcn_rcpf(x); }
__device__ __forceinline__ float rsq1(float x)  { return __builtin_amdgcn_rsqf(x); }
__device__ __forceinline__ float sqrt1(float x) { return __builtin_amdgcn_sqrtf(x); }

#define ACONST 4.4721439e-3f      // acos(1 - 1e-5)
#define PIF    3.14159265358979f
#define PImA   3.1371205f         // pi - ACONST
#define TWOPI  6.28318530717959f
#define INV2PI 0.15915494309189535f
#define CR2MIN 1.6e-9f            // |cr| < 4e-5  <=>  |K_SIGN*cr| < 4 (tanh unsat)

// Rare fix (|K*cr|<4): replace ideal sign(cr)*theta by reference's
// tanh(K*cr)*clamp(theta).  (Main loop counts only the exact -2pi*W.)
__device__ __forceinline__ float rare_fix(float cr, float dt)
{
    float ac = fabsf(cr), ad = fabsf(dt);
    float mn = fminf(ac, ad), mx = fmaxf(ac, ad);
    float q  = mn * rcp1(mx);
    float s2 = q * q;
    float r = fmaf(fmaf(fmaf(fmaf(0.0208351f, s2, -0.0851330f), s2,
                  0.1801410f), s2, -0.3302995f), s2, 0.9998660f) * q;
    r = (ac > ad) ? (1.57079632679f - r) : r;
    float theta = (dt < 0.0f) ? (PIF - r) : r;
    float thc = __builtin_amdgcn_fmed3f(theta, ACONST, PImA);  // EPS clamp
    float t  = cr * 100000.0f;
    float s  = t * t;
    float nm = t * fmaf(s + 105.0f, s, 945.0f);
    float qd = fmaf(fmaf(15.0f, s, 420.0f), s, 945.0f);
    float th = __builtin_amdgcn_fmed3f(nm * rcp1(qd), -1.0f, 1.0f);
    float scr = (cr >= 0.0f) ? 1.0f : -1.0f;
    return fmaf(th, thc, -scr * theta);
}

// Full-precision per-edge term for the cold fallback path.
__device__ __forceinline__ float edge_term_s(float cr, float dt)
{
    float n2 = fmaf(cr, cr, dt * dt);
    float co = dt * rsq1(n2);
    co = __builtin_amdgcn_fmed3f(co, -0.99999f, 0.99999f);
    float y = fabsf(co);
    float p = fmaf(fmaf(fmaf(-0.0187293f, y, 0.0742610f), y, -0.2121144f),
                   y, 1.5707288f);
    float a = sqrt1(1.0f - y) * p;
    a = (co >= 0.0f) ? a : (PIF - a);
    float t  = cr * 100000.0f;
    float s  = t * t;
    float nm = t * fmaf(s + 105.0f, s, 945.0f);
    float qd = fmaf(fmaf(15.0f, s, 420.0f), s, 945.0f);
    float th = __builtin_amdgcn_fmed3f(nm * rcp1(qd), -1.0f, 1.0f);
    return th * a;
}

__global__ __launch_bounds__(BLOCK, 6)
void contour_mask_kernel(const float2* __restrict__ contour,
                         const int* __restrict__ size_ptr,
                         float* __restrict__ out,
                         int out_size, int in0_elems)
{
    __shared__ float2 verts[65];

    const int size = *size_ptr;                // wave-uniform scalar load
    const int S2   = size * size;

    const int tid  = threadIdx.x;
    const int PIX_PER_BLOCK = (BLOCK / SPLIT) * PPT;     // 256
    const int base = blockIdx.x * PIX_PER_BLOCK;

    const int bn0 = base / S2;                 // uniform divide (once/wave)
    const int rem = base - bn0 * S2;
    const bool one_image = (rem + PIX_PER_BLOCK <= S2) &&
                           (base + PIX_PER_BLOCK <= out_size);
    // kv == 64 test without a divide: kv = in0_elems*S2/(2*out_size)
    const bool kv64 = ((long long)in0_elems * S2 == 128LL * out_size);
    const bool use_lds = kv64 && one_image;

    if (use_lds) {
        if (tid < 64)
            verts[tid] = contour[(size_t)bn0 * 64 + tid];
        if (tid == 0)
            verts[64] = contour[(size_t)bn0 * 64];   // wraparound duplicate
    }
    __syncthreads();

    const float inv_size = 1.0f / (float)size;

    // HOT: kv==64, 16 edges/seg x 4 segs, 4 consecutive pixels per thread.
    // vloc[17] = 34 VGPRs (was 66) -> target 8 waves/SIMD occupancy;
    // LDS preload traffic halved; float4 coalesced store.
    if (use_lds && (size & 3) == 0) {
        int pi0, pj0;
        if ((size & (size - 1)) == 0) {        // pow2 size: shifts not divides
            const int lg = 31 - __clz(size);
            pi0 = rem >> lg;
            pj0 = rem & (size - 1);
        } else {
            pi0 = rem / size;
            pj0 = rem - pi0 * size;
        }
        const int seg = tid & (SPLIT - 1);
        const int t   = tid & ~3;              // pixel-group offset (mult of 4)

        int pjA = pj0 + t, piA = pi0;
        while (pjA >= size) { pjA -= size; ++piA; }   // pjA stays mult of 4
        // group of 4 pixels shares the row: size%4==0 and pjA%4==0

        const float mx  = (float)piA * inv_size;      // mesh ch0 = i/size
        const float my0 = (float)pjA * inv_size;      // mesh ch1 = j/size

        const int k0 = seg * 16;

        // ---- preload the segment's 17 vertices into registers ----
        float2 vloc[17];
        #pragma unroll
        for (int k = 0; k < 17; ++k)
            vloc[k] = verts[k0 + k];

        float dx  = vloc[0].x - mx;
        float dy0 = vloc[0].y - my0;
        float dy1 = dy0 - inv_size;
        float dy2 = dy1 - inv_size;
        float dy3 = dy2 - inv_size;
        bool g0 = dy0 > 0.0f, g1 = dy1 > 0.0f;
        bool g2 = dy2 > 0.0f, g3 = dy3 > 0.0f;
        float S0 = 0.0f, S1 = 0.0f, S2f = 0.0f, S3 = 0.0f;   // -2pi*W accum
        bool a0 = false, a1 = false, a2 = false, a3 = false; // tanh-unsat flags

        #pragma unroll
        for (int k = 0; k < 16; ++k) {
            float rx  = vloc[k + 1].x - mx;    // register-resident vertex
            float ry0 = vloc[k + 1].y - my0;
            float ry1 = ry0 - inv_size;
            float ry2 = ry1 - inv_size;
            float ry3 = ry2 - inv_size;

            { // pixel 0: ray-crossing count only
                float cr = fmaf(dy0, rx, -(dx * ry0));
                bool rg = ry0 > 0.0f;
                float dS = 0.0f;
                dS = (!g0 && rg && cr < 0.0f) ? -TWOPI : dS;   // up
                dS = ( g0 && !rg && cr > 0.0f) ?  TWOPI : dS;  // down
                S0 += dS;
                a0 = a0 || (cr * cr < CR2MIN);
                dy0 = ry0; g0 = rg;
            }
            { // pixel 1
                float cr = fmaf(dy1, rx, -(dx * ry1));
                bool rg = ry1 > 0.0f;
                float dS = 0.0f;
                dS = (!g1 && rg && cr < 0.0f) ? -TWOPI : dS;
                dS = ( g1 && !rg && cr > 0.0f) ?  TWOPI : dS;
                S1 += dS;
                a1 = a1 || (cr * cr < CR2MIN);
                dy1 = ry1; g1 = rg;
            }
            { // pixel 2
                float cr = fmaf(dy2, rx, -(dx * ry2));
                bool rg = ry2 > 0.0f;
                float dS = 0.0f;
                dS = (!g2 && rg && cr < 0.0f) ? -TWOPI : dS;
                dS = ( g2 && !rg && cr > 0.0f) ?  TWOPI : dS;
                S2f += dS;
                a2 = a2 || (cr * cr < CR2MIN);
                dy2 = ry2; g2 = rg;
            }
            { // pixel 3
                float cr = fmaf(dy3, rx, -(dx * ry3));
                bool rg = ry3 > 0.0f;
                float dS = 0.0f;
                dS = (!g3 && rg && cr < 0.0f) ? -TWOPI : dS;
                dS = ( g3 && !rg && cr > 0.0f) ?  TWOPI : dS;
                S3 += dS;
                a3 = a3 || (cr * cr < CR2MIN);
                dy3 = ry3; g3 = rg;
            }
            dx = rx;
        }

        // rare pass: pixels near an edge line where tanh is unsaturated.
        // Recomputes cr with IDENTICAL chained expressions (sign consistency
        // with the main count).  Runtime loop; execz-skipped when no flags.
        if (a0 || a1 || a2 || a3) {
            float2 v0 = verts[k0];
            float dxr = v0.x - mx;
            float d0 = v0.y - my0;
            float d1 = d0 - inv_size;
            float d2 = d1 - inv_size;
            float d3 = d2 - inv_size;
            #pragma unroll 1
            for (int k = 0; k < 16; ++k) {
                float2 vn = verts[k0 + k + 1];
                float rx = vn.x - mx;
                float r0 = vn.y - my0;
                float r1 = r0 - inv_size;
                float r2 = r1 - inv_size;
                float r3 = r2 - inv_size;
                if (a0) {
                    float cr = fmaf(d0, rx, -(dxr * r0));
                    if (cr * cr < CR2MIN)
                        S0 += rare_fix(cr, fmaf(dxr, rx, d0 * r0));
                }
                if (a1) {
                    float cr = fmaf(d1, rx, -(dxr * r1));
                    if (cr * cr < CR2MIN)
                        S1 += rare_fix(cr, fmaf(dxr, rx, d1 * r1));
                }
                if (a2) {
                    float cr = fmaf(d2, rx, -(dxr * r2));
                    if (cr * cr < CR2MIN)
                        S2f += rare_fix(cr, fmaf(dxr, rx, d2 * r2));
                }
                if (a3) {
                    float cr = fmaf(d3, rx, -(dxr * r3));
                    if (cr * cr < CR2MIN)
                        S3 += rare_fix(cr, fmaf(dxr, rx, d3 * r3));
                }
                dxr = rx; d0 = r0; d1 = r1; d2 = r2; d3 = r3;
            }
        }

        // combine the 4 segments (butterfly within the 4-lane group)
        S0 += __shfl_xor(S0, 1, 64);  S0 += __shfl_xor(S0, 2, 64);
        S1 += __shfl_xor(S1, 1, 64);  S1 += __shfl_xor(S1, 2, 64);
        S2f += __shfl_xor(S2f, 1, 64); S2f += __shfl_xor(S2f, 2, 64);
        S3 += __shfl_xor(S3, 1, 64);  S3 += __shfl_xor(S3, 2, 64);

        if (seg == 0) {
            float4 res;
            res.x = fminf(fabsf(S0)  * INV2PI, 1.0f);
            res.y = fminf(fabsf(S1)  * INV2PI, 1.0f);
            res.z = fminf(fabsf(S2f) * INV2PI, 1.0f);
            res.w = fminf(fabsf(S3)  * INV2PI, 1.0f);
            *(float4*)(out + base + t) = res;  // coalesced 16B store
        }
        return;
    }

    // COLD fallback: generic sizes/kv, global-memory vertex reads
    const int bn_total = out_size / S2;
    const int kv       = in0_elems / (bn_total * 2);
    const int seg = tid & (SPLIT - 1);
    const int q   = (kv + SPLIT - 1) / SPLIT;
    const int k0c = min(seg * q, kv);
    const int k1c = min(k0c + q, kv);

    #pragma unroll
    for (int px = 0; px < PPT; ++px) {
        const int pixel = base + (tid >> 2) * PPT + px;
        float a = 0.0f;
        if (pixel < out_size && k0c < k1c) {
            const int bn = pixel / S2;
            const int p  = pixel - bn * S2;
            const int pi = p / size;
            const int pj = p - pi * size;
            const float mxs = pi * inv_size;
            const float mys = pj * inv_size;
            const float2* vsrc = contour + (size_t)bn * kv;
            float2 v = vsrc[k0c];
            float dx = v.x - mxs, dy = v.y - mys;
            for (int k = k0c; k < k1c; ++k) {
                int kn = k + 1; if (kn == kv) kn = 0;
                float2 vn = vsrc[kn];
                float rx = vn.x - mxs, ry = vn.y - mys;
                float cr = fmaf(dy, rx, -(dx * ry));
                float dt = fmaf(dx, rx, dy * ry);
                a += edge_term_s(cr, dt);
                dx = rx; dy = ry;
            }
        }
        a += __shfl_xor(a, 1, 64);
        a += __shfl_xor(a, 2, 64);
        if (pixel < out_size && seg == 0)
            out[pixel] = fminf(fabsf(a) * INV2PI, 1.0f);
    }
}

extern "C" void kernel_launch(void* const* d_in, const int* in_sizes, int n_in,
                              void* d_out, int out_size, void* d_ws, size_t ws_size,
                              hipStream_t stream)
{
    const float2* contour  = (const float2*)d_in[0];
    const int*    size_ptr = (const int*)d_in[1];
    float*        out      = (float*)d_out;

    const int PIX_PER_BLOCK = (BLOCK / SPLIT) * PPT;   // 256 pixels per block
    const int blocks = (out_size + PIX_PER_BLOCK - 1) / PIX_PER_BLOCK;
    contour_mask_kernel<<<blocks, BLOCK, 0, stream>>>(
        contour, size_ptr, out, out_size, in_sizes[0]);
}